// Round 1
// baseline (273.163 us; speedup 1.0000x reference)
//
#include <hip/hip_runtime.h>
#include <math.h>

#define T_STEPS 256
#define BS      512
#define N       2048
#define BLOCK   256
#define EPT     (N / BLOCK)   // 8 elements per thread
#define FUDGE   1e-4f

// One block per batch element k. Block owns w_out[k,:] in registers (8/thread).
// Per step: one fused block reduction of (sum w_out*h, sum h*h); norms derived
// as sqrt(FUDGE + (e*lr)^2 * sum_h2) -- algebraically identical to reference.
__global__ __launch_bounds__(BLOCK)
void legacy_elbo_scan_kernel(
    const float* __restrict__ noises,   // [T, BS]
    const float* __restrict__ ys,       // [T]
    const float* __restrict__ qs,       // [T]
    const float* __restrict__ z_biases, // [N]
    const float* __restrict__ w_in,     // [N]
    const float* __restrict__ w_inq,    // [N]
    const float* __restrict__ p_llr,    // log_learning_rate
    const float* __restrict__ p_llrd,   // log_learning_rate_decay
    const float* __restrict__ p_sigb,   // sigma_b
    const float* __restrict__ p_oscale, // output_scale
    const float* __restrict__ p_ufs,    // u_feedback_scale
    const float* __restrict__ p_lwd,    // log_weight_decay
    const float* __restrict__ p_qscale, // q_scale
    const float* __restrict__ p_tauq,   // tauqlpf_m1
    const float* __restrict__ p_tauy,   // tauylpf_m1
    float* __restrict__ out)            // [T, BS]
{
    const int tid  = threadIdx.x;
    const int blk  = blockIdx.x;      // batch index k
    const int lane = tid & 63;
    const int wid  = tid >> 6;        // 4 waves

    __shared__ float ys_s[T_STEPS];
    __shared__ float qs_s[T_STEPS];
    __shared__ float nz_s[T_STEPS];
    __shared__ float red[2][8];       // parity double-buffered partials

    // Stage per-step scalars (T == BLOCK == 256: one element per thread).
    ys_s[tid] = ys[tid];
    qs_s[tid] = qs[tid];
    nz_s[tid] = noises[tid * BS + blk];

    // Scalar params (broadcast loads; every thread computes identically).
    const float llr     = p_llr[0];
    const float llrd    = p_llrd[0];
    const float sigb    = p_sigb[0];
    const float oscale  = p_oscale[0];
    const float ufs     = p_ufs[0];
    const float lwd     = p_lwd[0];
    const float qscale  = p_qscale[0];
    const float tauq_m1 = p_tauq[0];
    const float tauy_m1 = p_tauy[0];

    const float lr0      = expf(llr);
    const float lr_decay = expf(llrd);
    const float wd       = expf(lwd);
    const float tauq     = 1.0f + log1pf(expf(tauq_m1));  // 1 + softplus
    const float tauy     = 1.0f + log1pf(expf(tauy_m1));
    const float omtq     = 1.0f - tauq;
    const float omty     = 1.0f - tauy;

    // Per-thread persistent state: 8 lanes of the N=2048 feature dim.
    float wout[EPT], bias[EPT], win[EPT], winq[EPT];
#pragma unroll
    for (int i = 0; i < EPT; ++i) {
        const int j = tid + i * BLOCK;     // coalesced
        bias[i] = sigb * z_biases[j];
        win[i]  = w_in[j];
        winq[i] = w_inq[j];
        wout[i] = 0.0f;
    }

    // Carry (identical scalar copies in every thread).
    float u = 0.0f, e = 0.0f, lr_mult = 1.0f, qlp = 0.0f, ylp = 0.0f;

    __syncthreads();

    for (int t = 0; t < T_STEPS; ++t) {
        const float q  = qs_s[t];
        const float y  = ys_s[t];
        const float nx = nz_s[t];

        qlp = omtq * qlp + tauq * q;
        const float qsc = qscale * qlp;
        const float x   = fmaf(u, ufs, e) + nx;   // uses previous u, e

        float su = 0.0f, sh2 = 0.0f;
        float h[EPT];
#pragma unroll
        for (int i = 0; i < EPT; ++i) {
            float hv = fmaf(x, win[i], fmaf(winq[i], qsc, bias[i]));
            hv = fmaxf(hv, 0.0f);
            h[i] = hv;
            su  = fmaf(wout[i], hv, su);   // uses pre-update w_out
            sh2 = fmaf(hv, hv, sh2);
        }

        // Wave-level butterfly reduction (64 lanes).
#pragma unroll
        for (int m = 1; m < 64; m <<= 1) {
            su  += __shfl_xor(su,  m, 64);
            sh2 += __shfl_xor(sh2, m, 64);
        }
        const int p = t & 1;
        if (lane == 0) {
            red[p][wid * 2]     = su;
            red[p][wid * 2 + 1] = sh2;
        }
        __syncthreads();   // single barrier per step (parity-safe)
        su  = red[p][0] + red[p][2] + red[p][4] + red[p][6];
        sh2 = red[p][1] + red[p][3] + red[p][5] + red[p][7];

        u = su;
        if (tid == 0) out[t * BS + blk] = oscale * u;

        ylp = omty * ylp + tauy * y;
        e = ylp - u;
        const float el = e * (lr0 * lr_mult);     // lr uses pre-update lr_mult

#pragma unroll
        for (int i = 0; i < EPT; ++i)
            wout[i] = wd * fmaf(el, h[i], wout[i]);   // wd*(w_out + dw)

        const float nrm = sqrtf(fmaf(el * el, sh2, FUDGE));
        lr_mult *= expf(-lr_decay * nrm);
    }
}

extern "C" void kernel_launch(void* const* d_in, const int* in_sizes, int n_in,
                              void* d_out, int out_size, void* d_ws, size_t ws_size,
                              hipStream_t stream) {
    (void)in_sizes; (void)n_in; (void)d_ws; (void)ws_size; (void)out_size;
    const float* noises   = (const float*)d_in[0];
    const float* ys       = (const float*)d_in[1];
    const float* qs       = (const float*)d_in[2];
    const float* z_biases = (const float*)d_in[3];
    const float* w_in     = (const float*)d_in[4];
    const float* w_inq    = (const float*)d_in[5];
    const float* llr      = (const float*)d_in[6];
    const float* llrd     = (const float*)d_in[7];
    const float* sigb     = (const float*)d_in[8];
    const float* oscale   = (const float*)d_in[9];
    const float* ufs      = (const float*)d_in[10];
    const float* lwd      = (const float*)d_in[11];
    const float* qscale   = (const float*)d_in[12];
    const float* tauq     = (const float*)d_in[13];
    const float* tauy     = (const float*)d_in[14];
    float* out = (float*)d_out;

    hipLaunchKernelGGL(legacy_elbo_scan_kernel, dim3(BS), dim3(BLOCK), 0, stream,
                       noises, ys, qs, z_biases, w_in, w_inq,
                       llr, llrd, sigb, oscale, ufs, lwd, qscale, tauq, tauy,
                       out);
}

// Round 3
// 237.927 us; speedup vs baseline: 1.1481x; 1.1481x over previous
//
#include <hip/hip_runtime.h>
#include <math.h>

#define T_STEPS 256
#define BS      512
#define N       2048
#define WAVE    64
#define EPT     (N / WAVE)    // 32 elements per thread
#define FUDGE   1e-4f

// --- wave64 all-lanes sum via DPP (GCN classic) -------------------------
// row_shr:1,2,4,8 -> lane15/31/47/63 hold row sums; row_bcast15, row_bcast31
// accumulate across rows so lane 63 holds the wave total; readlane 63
// broadcasts it to all lanes as an SGPR (uniform).
template <int CTRL>
__device__ __forceinline__ float dpp_add(float v) {
    int sh = __builtin_amdgcn_update_dpp(0, __float_as_int(v), CTRL, 0xf, 0xf, true);
    return v + __int_as_float(sh);
}

__device__ __forceinline__ float wave_allsum(float v) {
    v = dpp_add<0x111>(v);  // row_shr:1
    v = dpp_add<0x112>(v);  // row_shr:2
    v = dpp_add<0x114>(v);  // row_shr:4
    v = dpp_add<0x118>(v);  // row_shr:8
    v = dpp_add<0x142>(v);  // row_bcast:15
    v = dpp_add<0x143>(v);  // row_bcast:31
    return __int_as_float(__builtin_amdgcn_readlane(__float_as_int(v), 63));
}

// One WAVE per batch element: no __syncthreads in the scan loop, all
// cross-lane traffic is DPP. w_out kept as  w_t = sp_t * v_t  with scalar
// sp_t = wd^t, so the per-element update is a single fma:
//   w_{t+1} = wd*(w_t + el*h)  ==>  v += (el/sp)*h ; sp *= wd
__global__ __launch_bounds__(WAVE, 1)
void legacy_elbo_scan_kernel(
    const float* __restrict__ noises,   // [T, BS]
    const float* __restrict__ ys,       // [T]
    const float* __restrict__ qs,       // [T]
    const float* __restrict__ z_biases, // [N]
    const float* __restrict__ w_in,     // [N]
    const float* __restrict__ w_inq,    // [N]
    const float* __restrict__ p_llr,
    const float* __restrict__ p_llrd,
    const float* __restrict__ p_sigb,
    const float* __restrict__ p_oscale,
    const float* __restrict__ p_ufs,
    const float* __restrict__ p_lwd,
    const float* __restrict__ p_qscale,
    const float* __restrict__ p_tauq,
    const float* __restrict__ p_tauy,
    float* __restrict__ out)            // [T, BS]
{
    const int lane = threadIdx.x;       // 0..63
    const int blk  = blockIdx.x;        // batch index k

    __shared__ float ys_s[T_STEPS];
    __shared__ float qs_s[T_STEPS];
    __shared__ float nz_s[T_STEPS];

    // Stage per-step scalars: 4 rounds of 64.
#pragma unroll
    for (int i = 0; i < T_STEPS / WAVE; ++i) {
        const int t = lane + (i << 6);
        ys_s[t] = ys[t];
        qs_s[t] = qs[t];
        nz_s[t] = noises[t * BS + blk];
    }

    const float llr     = p_llr[0];
    const float llrd    = p_llrd[0];
    const float sigb    = p_sigb[0];
    const float oscale  = p_oscale[0];
    const float ufs     = p_ufs[0];
    const float lwd     = p_lwd[0];
    const float qscale  = p_qscale[0];
    const float tauq_m1 = p_tauq[0];
    const float tauy_m1 = p_tauy[0];

    const float lr0      = expf(llr);
    const float lr_decay = expf(llrd);
    const float wd       = expf(lwd);
    const float rwd      = 1.0f / wd;
    const float tauq     = 1.0f + log1pf(expf(tauq_m1));
    const float tauy     = 1.0f + log1pf(expf(tauy_m1));
    const float omtq     = 1.0f - tauq;
    const float omty     = 1.0f - tauy;

    // Persistent per-thread state: 32 lanes of the feature dim, coalesced.
    float v[EPT], bias[EPT], win[EPT], winq[EPT];
#pragma unroll
    for (int i = 0; i < EPT; ++i) {
        const int j = lane + i * WAVE;
        bias[i] = sigb * z_biases[j];
        win[i]  = w_in[j];
        winq[i] = w_inq[j];
        v[i]    = 0.0f;
    }

    float u = 0.0f, e = 0.0f, lr_mult = 1.0f, qlp = 0.0f, ylp = 0.0f;
    float sp = 1.0f, rsp = 1.0f;        // wd^t and 1/wd^t

    __syncthreads();                    // drain staging (single wave)

    // Prefetch step-0 scalars.
    float q_c = qs_s[0], y_c = ys_s[0], n_c = nz_s[0];

    for (int t = 0; t < T_STEPS; ++t) {
        // Prefetch next step's scalars (hide LDS latency behind the h-loop).
        const int tn = (t + 1 < T_STEPS) ? t + 1 : t;
        const float q_n = qs_s[tn], y_n = ys_s[tn], n_n = nz_s[tn];

        qlp = omtq * qlp + tauq * q_c;
        const float qsc = qscale * qlp;
        const float x   = fmaf(u, ufs, e) + n_c;

        float su[4]  = {0.f, 0.f, 0.f, 0.f};
        float sh[4]  = {0.f, 0.f, 0.f, 0.f};
        float h[EPT];
#pragma unroll
        for (int i = 0; i < EPT; ++i) {
            float hv = fmaf(x, win[i], fmaf(winq[i], qsc, bias[i]));
            hv = fmaxf(hv, 0.0f);
            h[i] = hv;
            su[i & 3] = fmaf(v[i], hv, su[i & 3]);
            sh[i & 3] = fmaf(hv, hv, sh[i & 3]);
        }
        const float su_t = wave_allsum((su[0] + su[1]) + (su[2] + su[3]));
        const float sh2  = wave_allsum((sh[0] + sh[1]) + (sh[2] + sh[3]));

        u = sp * su_t;                  // w_t = sp * v_t
        if (lane == 0) out[t * BS + blk] = oscale * u;

        ylp = omty * ylp + tauy * y_c;
        e = ylp - u;
        const float el = e * (lr0 * lr_mult);
        const float c  = el * rsp;      // dw in v-space

#pragma unroll
        for (int i = 0; i < EPT; ++i)
            v[i] = fmaf(c, h[i], v[i]);

        const float nrm = sqrtf(fmaf(el * el, sh2, FUDGE));
        lr_mult *= expf(-lr_decay * nrm);
        sp  *= wd;
        rsp *= rwd;

        q_c = q_n; y_c = y_n; n_c = n_n;
    }
}

extern "C" void kernel_launch(void* const* d_in, const int* in_sizes, int n_in,
                              void* d_out, int out_size, void* d_ws, size_t ws_size,
                              hipStream_t stream) {
    (void)in_sizes; (void)n_in; (void)d_ws; (void)ws_size; (void)out_size;
    const float* noises   = (const float*)d_in[0];
    const float* ys       = (const float*)d_in[1];
    const float* qs       = (const float*)d_in[2];
    const float* z_biases = (const float*)d_in[3];
    const float* w_in     = (const float*)d_in[4];
    const float* w_inq    = (const float*)d_in[5];
    const float* llr      = (const float*)d_in[6];
    const float* llrd     = (const float*)d_in[7];
    const float* sigb     = (const float*)d_in[8];
    const float* oscale   = (const float*)d_in[9];
    const float* ufs      = (const float*)d_in[10];
    const float* lwd      = (const float*)d_in[11];
    const float* qscale   = (const float*)d_in[12];
    const float* tauq     = (const float*)d_in[13];
    const float* tauy     = (const float*)d_in[14];
    float* out = (float*)d_out;

    hipLaunchKernelGGL(legacy_elbo_scan_kernel, dim3(BS), dim3(WAVE), 0, stream,
                       noises, ys, qs, z_biases, w_in, w_inq,
                       llr, llrd, sigb, oscale, ufs, lwd, qscale, tauq, tauy,
                       out);
}